// Round 5
// baseline (1773.753 us; speedup 1.0000x reference)
//
#include <hip/hip_runtime.h>
#include <math.h>

#define B_ 256
#define D_ 564
#define S_ 40
#define NB_ 6
#define N_ 2256          // 4*D
#define M_ 10240         // B*S
#define DD_ 318096       // D*D
#define KP_ 576          // D padded to multiple of 32 for MFMA K
#define OUTIN_ 1128
#define HW_ 288          // u32 words per h row (576 f16)
#define BSTRIDE_ 32      // u32 stride between per-bg barrier counters (128 B)

typedef _Float16 f16;
typedef _Float16 f16x4 __attribute__((ext_vector_type(4)));
typedef _Float16 f16x8 __attribute__((ext_vector_type(8)));
typedef float    f32x4 __attribute__((ext_vector_type(4)));

// ---------------------------------------------------------------------------
// P) prep: W,R (l,g,k,e) fp32 -> fp16, k padded 564->576 with zeros.
//    R kept as (l,g,e,k).  W written GATE-INTERLEAVED: (l, e*4+g, k).
// ---------------------------------------------------------------------------
__global__ __launch_bounds__(256) void k_prep(const float* __restrict__ Wg,
                                              const float* __restrict__ Rg,
                                              f16* __restrict__ Wt,
                                              f16* __restrict__ Rt) {
    __shared__ float tile[32][33];
    int bz  = blockIdx.z;            // 0..47
    int sel = bz / 24;               // 0 = W, 1 = R
    int lg  = bz - sel * 24;         // layer*4 + gate
    const float* src = (sel ? Rg : Wg) + (size_t)lg * DD_;
    int k0 = blockIdx.x * 32, e0 = blockIdx.y * 32;
    int j = threadIdx.x & 31;
    for (int i = threadIdx.x >> 5; i < 32; i += 8) {
        int k = k0 + i, e = e0 + j;
        tile[i][j] = (k < D_ && e < D_) ? src[(size_t)k * D_ + e] : 0.f;
    }
    __syncthreads();
    if (sel) {
        f16* dst = Rt + (size_t)lg * (D_ * KP_);
        for (int i = threadIdx.x >> 5; i < 32; i += 8) {
            int e = e0 + i, k = k0 + j;
            if (e < D_) dst[(size_t)e * KP_ + k] = (f16)tile[j][i];
        }
    } else {
        int layer = lg >> 2, gate = lg & 3;
        f16* dst = Wt + (size_t)layer * (4 * (size_t)D_ * KP_);
        for (int i = threadIdx.x >> 5; i < 32; i += 8) {
            int e = e0 + i, k = k0 + j;
            if (e < D_) dst[((size_t)e * 4 + gate) * KP_ + k] = (f16)tile[j][i];
        }
    }
}

// ---------------------------------------------------------------------------
// 0) transpose inp (B, D, S) -> x (B, S, D)
// ---------------------------------------------------------------------------
__global__ __launch_bounds__(256) void k_transpose(const float* __restrict__ inp,
                                                   float* __restrict__ x) {
    __shared__ float tile[64][41];
    int b  = blockIdx.y;
    int d0 = blockIdx.x * 64;
    const float* ip = inp + (size_t)b * (D_ * S_);
    for (int idx = threadIdx.x; idx < 64 * 40; idx += 256) {
        int i = idx / 40, s = idx - i * 40;
        if (d0 + i < D_) tile[i][s] = ip[(size_t)(d0 + i) * S_ + s];
    }
    __syncthreads();
    float* xp = x + (size_t)b * (D_ * S_);
    for (int idx = threadIdx.x; idx < 40 * 64; idx += 256) {
        int j = idx & 63, s = idx >> 6;
        if (d0 + j < D_) xp[(size_t)s * D_ + d0 + j] = tile[j][s];
    }
}

// ---------------------------------------------------------------------------
// 1) fused: x += h (prev layer, optional) + LayerNorm row stats
//    h layout (S, B, KP) f16
// ---------------------------------------------------------------------------
__global__ __launch_bounds__(256) void k_addh_lnstats(float* __restrict__ x,
                                                      const f16* __restrict__ h,
                                                      int addh,
                                                      float* __restrict__ lmu,
                                                      float* __restrict__ lrs) {
    int row  = blockIdx.x * 4 + (threadIdx.x >> 6);
    int lane = threadIdx.x & 63;
    float* xp = x + (size_t)row * D_;
    int b = row / S_, s = row - b * S_;
    const f16* hp = h + ((size_t)s * B_ + b) * KP_;
    float s1 = 0.f, s2 = 0.f;
    if (addh) {
        for (int i = lane; i < D_; i += 64) {
            float v = xp[i] + (float)hp[i];
            xp[i] = v;
            s1 += v;
            s2 += v * v;
        }
    } else {
        for (int i = lane; i < D_; i += 64) {
            float v = xp[i];
            s1 += v;
            s2 += v * v;
        }
    }
    for (int off = 32; off; off >>= 1) {
        s1 += __shfl_down(s1, off);
        s2 += __shfl_down(s2, off);
    }
    if (lane == 0) {
        float mu  = s1 * (1.f / D_);
        float var = fmaxf(s2 * (1.f / D_) - mu * mu, 0.f);
        lmu[row] = mu;
        lrs[row] = rsqrtf(var + 1e-5f);
    }
}

// ---------------------------------------------------------------------------
// 1b) apply LN + fp16 convert: hA (10240, 576) fp16, pad zeros
// ---------------------------------------------------------------------------
__global__ __launch_bounds__(256) void k_lnapply(const float* __restrict__ x,
                                                 const float* __restrict__ lg,
                                                 const float* __restrict__ lb,
                                                 const float* __restrict__ lmu,
                                                 const float* __restrict__ lrs,
                                                 f16* __restrict__ hA) {
    int idx = blockIdx.x * 256 + threadIdx.x;   // M_*72 slots
    int row = idx / 72, kq = idx - row * 72;
    int k   = kq * 8;
    float mu = lmu[row], rs = lrs[row];
    const float* xp = x + (size_t)row * D_;
    f16x8 o;
    if (kq < 70) {
        float4 v0 = *(const float4*)(xp + k);
        float4 v1 = *(const float4*)(xp + k + 4);
        float4 g0 = *(const float4*)(lg + k);
        float4 g1 = *(const float4*)(lg + k + 4);
        float4 b0 = *(const float4*)(lb + k);
        float4 b1 = *(const float4*)(lb + k + 4);
        o[0] = (f16)((v0.x - mu) * rs * g0.x + b0.x);
        o[1] = (f16)((v0.y - mu) * rs * g0.y + b0.y);
        o[2] = (f16)((v0.z - mu) * rs * g0.z + b0.z);
        o[3] = (f16)((v0.w - mu) * rs * g0.w + b0.w);
        o[4] = (f16)((v1.x - mu) * rs * g1.x + b1.x);
        o[5] = (f16)((v1.y - mu) * rs * g1.y + b1.y);
        o[6] = (f16)((v1.z - mu) * rs * g1.z + b1.z);
        o[7] = (f16)((v1.w - mu) * rs * g1.w + b1.w);
    } else {
#pragma unroll
        for (int j = 0; j < 8; ++j) {
            int kk = k + j;
            float v = (kk < D_) ? (xp[kk] - mu) * rs * lg[kk] + lb[kk] : 0.f;
            o[j] = (f16)v;
        }
    }
    *(f16x8*)(hA + (size_t)row * KP_ + k) = o;
}

// ---------------------------------------------------------------------------
// 2) persistent sLSTM recurrence with FUSED pre-GEMM.
//    k_pregemm/pre2 are gone: each block holds its 144 W columns in 36
//    f16x8 registers (loaded once per layer, like breg) and computes
//    gates(t) = bias + hA[b,t]·W + h(t-1)·R per step.  The W-MFMA runs
//    BEFORE the poll (hidden in the wait); hA rows are double-buffered in
//    LDS and prefetched one step ahead through registers (no dependency).
//    Synchronization protocol is round-1 VERBATIM (best measured: shared
//    per-bg counter, sc0sc1 single-poller, vmcnt-draining syncthreads,
//    agent-scope RMW arrive — RMW arrive REQUIRED, plain store raced).
// ---------------------------------------------------------------------------
__global__ __launch_bounds__(576, 1) void k_rec_persist(
        const f16* __restrict__ Rt,      // (4*564, 576) layer slice, (g,e) rows
        const f16* __restrict__ Wt,      // (2256, 576) layer slice, e*4+g rows
        const f16* __restrict__ hA,      // (10240, 576) LN'd activations
        unsigned* __restrict__ hbuf,     // (40, 256, 288) u32
        unsigned* __restrict__ bar,      // 16 counters, stride BSTRIDE_ u32
        const float* __restrict__ bgl,   // (4, 564) f32 bias
        int layer) {
    __shared__ __align__(16) f16 hs[16 * 584];          // h tile, padded rows
    __shared__ __align__(16) f16 haA[2][16 * 584];      // hA rows, dbuf
    __shared__ __align__(16) float gbuf[144 * 17 + 2];  // stride-17

    const int tid  = threadIdx.x;
    const int et   = blockIdx.x;
    const int bg   = blockIdx.y;
    const int wave = tid >> 6, lane = tid & 63;
    const int quad = lane >> 4, l16 = lane & 15;

    unsigned* barp = bar + bg * BSTRIDE_;
    const unsigned base = (unsigned)layer * 640u;   // 16 arrives x 40 steps

    const int c  = wave * 16 + l16;                 // 0..143
    const int g  = c / 36, el = c - g * 36;
    const int e  = et * 36 + el;
    const int ec = (e < D_) ? e : D_ - 1;

    // R fragments: col c -> Rt row g*D+e;  W fragments: col c -> Wt row e*4+g
    f16x8 breg[18], wreg[18];
    {
        const f16* rp = Rt + (size_t)(g * D_ + ec) * KP_ + quad * 8;
        const f16* wp = Wt + (size_t)(ec * 4 + g) * KP_ + quad * 8;
#pragma unroll
        for (int kc = 0; kc < 18; ++kc) {
            breg[kc] = *(const f16x8*)(rp + kc * 32);
            wreg[kc] = *(const f16x8*)(wp + kc * 32);
        }
    }
    const float bbias = bgl[g * D_ + ec];

    const int b_loc = tid & 15, el2 = tid >> 4;
    const int e2  = et * 36 + el2;
    const int b   = bg * 16 + b_loc;
    const bool eok = (e2 < D_);

    // hA staging role: thread covers rows hr, hr+8 at 16B-col hq
    const int hr = tid / 72, hq = tid - (tid / 72) * 72;
    const f16* haRow0 = hA + (size_t)(bg * 16 + hr) * S_ * KP_ + hq * 8;
    const f16* haRow1 = hA + (size_t)(bg * 16 + hr + 8) * S_ * KP_ + hq * 8;

    float cv = 0.f, nv = 0.f, mv = 0.f;

    // prologue: stage hA rows for t=0
    *(f16x8*)(haA[0] + hr * 584 + hq * 8)       = *(const f16x8*)(haRow0);
    *(f16x8*)(haA[0] + (hr + 8) * 584 + hq * 8) = *(const f16x8*)(haRow1);
    __syncthreads();

    int cur = 0;
    for (int t = 0; t < S_; ++t) {
        // ---- W-part (independent of exchange; hides under the wait) ----
        f32x4 a0 = (f32x4){0.f, 0.f, 0.f, 0.f};
        f32x4 a1 = (f32x4){0.f, 0.f, 0.f, 0.f};
        {
            const f16* al = haA[cur] + l16 * 584 + quad * 8;
#pragma unroll
            for (int kc = 0; kc < 18; kc += 2) {
                f16x8 f0 = *(const f16x8*)(al + kc * 32);
                f16x8 f1 = *(const f16x8*)(al + kc * 32 + 32);
                a0 = __builtin_amdgcn_mfma_f32_16x16x32_f16(f0, wreg[kc],     a0, 0, 0, 0);
                a1 = __builtin_amdgcn_mfma_f32_16x16x32_f16(f1, wreg[kc + 1], a1, 0, 0, 0);
            }
        }
        // prefetch next step's hA rows into registers (no dependency)
        f16x8 pre0, pre1;
        if (t + 1 < S_) {
            pre0 = *(const f16x8*)(haRow0 + (size_t)(t + 1) * KP_);
            pre1 = *(const f16x8*)(haRow1 + (size_t)(t + 1) * KP_);
        }

        if (t > 0) {
            if (tid == 0) {
                unsigned tgt = base + 16u * (unsigned)t;
                for (;;) {
                    unsigned v;
                    asm volatile(
                        "global_load_dword %0, %1, off sc0 sc1\n\t"
                        "s_waitcnt vmcnt(0)"
                        : "=v"(v) : "v"(barp) : "memory");
                    if (v >= tgt) break;
                    __builtin_amdgcn_s_sleep(1);
                }
            }
            __syncthreads();
            const unsigned long long* hsrc = (const unsigned long long*)
                (hbuf + (size_t)(t - 1) * (B_ * HW_) + (size_t)bg * 16 * HW_);
#pragma unroll
            for (int p = 0; p < 4; ++p) {
                int ch  = tid + p * 576;
                int row = ch / 144, col = ch - row * 144;
                unsigned long long v = __hip_atomic_load(
                    hsrc + (size_t)row * 144 + col,
                    __ATOMIC_RELAXED, __HIP_MEMORY_SCOPE_AGENT);
                *(unsigned long long*)(hs + row * 584 + col * 4) = v;
            }
            __syncthreads();
            const f16* hl = hs + l16 * 584 + quad * 8;
#pragma unroll
            for (int kc = 0; kc < 18; kc += 2) {
                f16x8 f0 = *(const f16x8*)(hl + kc * 32);
                f16x8 f1 = *(const f16x8*)(hl + kc * 32 + 32);
                a0 = __builtin_amdgcn_mfma_f32_16x16x32_f16(f0, breg[kc],     a0, 0, 0, 0);
                a1 = __builtin_amdgcn_mfma_f32_16x16x32_f16(f1, breg[kc + 1], a1, 0, 0, 0);
            }
        }
        f32x4 acc = a0 + a1;
#pragma unroll
        for (int r = 0; r < 4; ++r)
            gbuf[c * 17 + quad * 4 + r] = acc[r] + bbias;
        __syncthreads();

        float hn = 0.f;
        if (eok) {
            float it = gbuf[(0 * 36 + el2) * 17 + b_loc];
            float ft = gbuf[(1 * 36 + el2) * 17 + b_loc];
            float zt = gbuf[(2 * 36 + el2) * 17 + b_loc];
            float ot = gbuf[(3 * 36 + el2) * 17 + b_loc];
            float mn = fmaxf(ft + mv, it);
            float iv = __expf(it - mn);
            float fv = __expf(ft + mv - mn);
            // tanh(z) = 1 - 2/(exp(2z)+1): exact at +/-inf, NaN-free
            float th = 1.f - 2.f * __builtin_amdgcn_rcpf(__expf(2.f * zt) + 1.f);
            float cn = fv * cv + iv * th;
            float nn = fv * nv + iv;
            float sg = __builtin_amdgcn_rcpf(1.f + __expf(-ot));
            hn = cn * __builtin_amdgcn_rcpf(fmaxf(nn, 1e-6f)) * sg;
            cv = cn; nv = nn; mv = mn;
        }

        unsigned short h16 = __builtin_bit_cast(unsigned short, (f16)hn);
        int other = __shfl_xor((int)h16, 16);
        if ((el2 & 1) == 0) {
            unsigned word = (unsigned)h16 | ((unsigned)(unsigned short)other << 16);
            __hip_atomic_store(hbuf + (size_t)t * (B_ * HW_)
                                    + (size_t)b * HW_ + et * 18 + (el2 >> 1),
                               word, __ATOMIC_RELAXED, __HIP_MEMORY_SCOPE_AGENT);
        }

        // stage next hA tile into the other buffer (before the drain barrier)
        if (t + 1 < S_) {
            *(f16x8*)(haA[cur ^ 1] + hr * 584 + hq * 8)       = pre0;
            *(f16x8*)(haA[cur ^ 1] + (hr + 8) * 584 + hq * 8) = pre1;
        }

        // arrive: syncthreads drains vmcnt in every wave; RMW arrive lands
        // behind the drained h stores at the coherence point.
        __syncthreads();
        if (tid == 0)
            __hip_atomic_fetch_add(barp, 1u, __ATOMIC_RELAXED,
                                   __HIP_MEMORY_SCOPE_AGENT);
        cur ^= 1;
    }
}

// ---------------------------------------------------------------------------
// 4) BatchNorm part 1: fold in layer-5 h (x += h, writeback) + partial sums.
// ---------------------------------------------------------------------------
__global__ __launch_bounds__(256) void k_bnpart(float* __restrict__ x,
                                                const f16* __restrict__ h,
                                                float* __restrict__ part) {
    int b = blockIdx.x;
    for (int c = threadIdx.x; c < D_; c += 256) {
        float s1 = 0.f, s2 = 0.f;
        for (int t = 0; t < S_; ++t) {
            size_t xi = (size_t)(b * S_ + t) * D_ + c;
            float v = x[xi] + (float)h[((size_t)t * B_ + b) * KP_ + c];
            x[xi] = v;
            s1 += v;
            s2 += v * v;
        }
        part[(size_t)b * 1152 + c]       = s1;
        part[(size_t)b * 1152 + 576 + c] = s2;
    }
}

__global__ __launch_bounds__(64) void k_bnfinal(const float* __restrict__ part,
                                                const float* __restrict__ bn_g,
                                                const float* __restrict__ bn_b,
                                                float* __restrict__ sc,
                                                float* __restrict__ sh) {
    int d = blockIdx.x * 64 + threadIdx.x;
    if (d >= D_) return;
    float s1 = 0.f, s2 = 0.f;
    for (int w = 0; w < 256; ++w) {
        s1 += part[(size_t)w * 1152 + d];
        s2 += part[(size_t)w * 1152 + 576 + d];
    }
    float mu  = s1 * (1.f / M_);
    float var = fmaxf(s2 * (1.f / M_) - mu * mu, 0.f);
    float s   = bn_g[d] * rsqrtf(var + 1e-5f);
    sc[d] = s;
    sh[d] = bn_b[d] - mu * s;
}

// ---------------------------------------------------------------------------
// 5) final projection + tanh
// ---------------------------------------------------------------------------
__global__ __launch_bounds__(128) void k_final(const float* __restrict__ x,
                                               const float* __restrict__ sc,
                                               const float* __restrict__ sh,
                                               const float* __restrict__ w6,
                                               const float* __restrict__ b6,
                                               float* __restrict__ out) {
    int b = blockIdx.x / 20;
    int p = blockIdx.x - b * 20;
    float a0 = 0.f, a1 = 0.f;
    for (int q = threadIdx.x; q < OUTIN_; q += 128) {
        int u = p * OUTIN_ + q;
        int d = u / 40, s = u - d * 40;
        float v = x[((size_t)b * S_ + s) * D_ + d] * sc[d] + sh[d];
        a0 = fmaf(v, w6[q * 2 + 0], a0);
        a1 = fmaf(v, w6[q * 2 + 1], a1);
    }
    __shared__ float r0[128], r1[128];
    r0[threadIdx.x] = a0;
    r1[threadIdx.x] = a1;
    __syncthreads();
    for (int off = 64; off; off >>= 1) {
        if (threadIdx.x < off) {
            r0[threadIdx.x] += r0[threadIdx.x + off];
            r1[threadIdx.x] += r1[threadIdx.x + off];
        }
        __syncthreads();
    }
    if (threadIdx.x == 0) {
        out[((size_t)b * 20 + p) * 2 + 0] = tanhf(r0[0] + b6[0]);
        out[((size_t)b * 20 + p) * 2 + 1] = tanhf(r1[0] + b6[1]);
    }
}

// ---------------------------------------------------------------------------
extern "C" void kernel_launch(void* const* d_in, const int* in_sizes, int n_in,
                              void* d_out, int out_size, void* d_ws, size_t ws_size,
                              hipStream_t stream) {
    const float* inp  = (const float*)d_in[0];
    const float* Wg   = (const float*)d_in[1];
    const float* Rg   = (const float*)d_in[2];
    const float* bg   = (const float*)d_in[3];
    const float* ln_g = (const float*)d_in[4];
    const float* ln_b = (const float*)d_in[5];
    const float* bn_g = (const float*)d_in[6];
    const float* bn_b = (const float*)d_in[7];
    const float* w6   = (const float*)d_in[8];
    const float* b6   = (const float*)d_in[9];
    float* out = (float*)d_out;

    float* ws = (float*)d_ws;
    size_t off = 0;
    float*    x    = ws + off;            off += (size_t)M_ * D_;
    f16*      hA   = (f16*)(ws + off);    off += (size_t)M_ * KP_ / 2;  // 11.8 MB
    unsigned* hbuf = (unsigned*)(ws + off); off += (size_t)M_ * KP_ / 2; // 11.8 MB (separate: rec reads hA while writing hbuf)
    f16*      Wt   = (f16*)(ws + off);    off += (size_t)NB_ * 4 * D_ * KP_ / 2;
    f16*      Rt   = (f16*)(ws + off);    off += (size_t)NB_ * 4 * D_ * KP_ / 2;
    float*    lmu  = ws + off;            off += M_;
    float*    lrs  = ws + off;            off += M_;
    float*    part = ws + off;            off += 256 * 1152;
    float*    sc   = ws + off;            off += 576;
    float*    sh   = ws + off;            off += 576;
    unsigned* bar  = (unsigned*)(ws + off); off += 16 * BSTRIDE_;

    hipMemsetAsync(bar, 0, 16 * BSTRIDE_ * sizeof(unsigned), stream);

    k_prep<<<dim3(18, 18, 48), 256, 0, stream>>>(Wg, Rg, Wt, Rt);
    k_transpose<<<dim3(9, B_), 256, 0, stream>>>(inp, x);

    for (int l = 0; l < NB_; ++l) {
        const f16*   Wtl = Wt + (size_t)l * 4 * D_ * KP_;
        const f16*   Rtl = Rt + (size_t)l * 4 * D_ * KP_;
        const float* bgl = bg + (size_t)l * N_;
        const float* lgl = ln_g + (size_t)l * D_;
        const float* lbl = ln_b + (size_t)l * D_;

        k_addh_lnstats<<<M_ / 4, 256, 0, stream>>>(x, (const f16*)hbuf,
                                                   l > 0 ? 1 : 0, lmu, lrs);
        k_lnapply<<<M_ * 72 / 256, 256, 0, stream>>>(x, lgl, lbl, lmu, lrs, hA);
        k_rec_persist<<<dim3(16, 16), 576, 0, stream>>>(Rtl, Wtl, hA, hbuf,
                                                        bar, bgl, l);
    }

    k_bnpart<<<B_, 256, 0, stream>>>(x, (const f16*)hbuf, part);
    k_bnfinal<<<9, 64, 0, stream>>>(part, bn_g, bn_b, sc, sh);
    k_final<<<B_ * 20, 128, 0, stream>>>(x, sc, sh, w6, b6, out);
}

// Round 6
// 1361.385 us; speedup vs baseline: 1.3029x; 1.3029x over previous
//
#include <hip/hip_runtime.h>
#include <math.h>

#define B_ 256
#define D_ 564
#define S_ 40
#define NB_ 6
#define N_ 2256          // 4*D
#define M_ 10240         // B*S
#define DD_ 318096       // D*D
#define KP_ 576          // D padded to multiple of 32 for MFMA K
#define OUTIN_ 1128
#define HW_ 288          // u32 words per h row (576 f16)
#define BSTRIDE_ 32      // u32 stride between per-bg barrier counters (128 B)

typedef _Float16 f16;
typedef _Float16 f16x4 __attribute__((ext_vector_type(4)));
typedef _Float16 f16x8 __attribute__((ext_vector_type(8)));
typedef float    f32x4 __attribute__((ext_vector_type(4)));

// async global->LDS, 16 B per lane; LDS dest = wave-uniform base + lane*16.
__device__ __forceinline__ void gload16(const f16* g, f16* l) {
    __builtin_amdgcn_global_load_lds(
        (__attribute__((address_space(1))) void*)g,
        (__attribute__((address_space(3))) void*)l, 16, 0, 0);
}

// ---------------------------------------------------------------------------
// P) prep: W,R (l,g,k,e) fp32 -> fp16, k padded 564->576 with zeros.
//    R kept as (l,g,e,k).  W written GATE-INTERLEAVED: (l, e*4+g, k).
// ---------------------------------------------------------------------------
__global__ __launch_bounds__(256) void k_prep(const float* __restrict__ Wg,
                                              const float* __restrict__ Rg,
                                              f16* __restrict__ Wt,
                                              f16* __restrict__ Rt) {
    __shared__ float tile[32][33];
    int bz  = blockIdx.z;            // 0..47
    int sel = bz / 24;               // 0 = W, 1 = R
    int lg  = bz - sel * 24;         // layer*4 + gate
    const float* src = (sel ? Rg : Wg) + (size_t)lg * DD_;
    int k0 = blockIdx.x * 32, e0 = blockIdx.y * 32;
    int j = threadIdx.x & 31;
    for (int i = threadIdx.x >> 5; i < 32; i += 8) {
        int k = k0 + i, e = e0 + j;
        tile[i][j] = (k < D_ && e < D_) ? src[(size_t)k * D_ + e] : 0.f;
    }
    __syncthreads();
    if (sel) {
        f16* dst = Rt + (size_t)lg * (D_ * KP_);
        for (int i = threadIdx.x >> 5; i < 32; i += 8) {
            int e = e0 + i, k = k0 + j;
            if (e < D_) dst[(size_t)e * KP_ + k] = (f16)tile[j][i];
        }
    } else {
        int layer = lg >> 2, gate = lg & 3;
        f16* dst = Wt + (size_t)layer * (4 * (size_t)D_ * KP_);
        for (int i = threadIdx.x >> 5; i < 32; i += 8) {
            int e = e0 + i, k = k0 + j;
            if (e < D_) dst[((size_t)e * 4 + gate) * KP_ + k] = (f16)tile[j][i];
        }
    }
}

// ---------------------------------------------------------------------------
// 0) transpose inp (B, D, S) -> x (B, S, D)
// ---------------------------------------------------------------------------
__global__ __launch_bounds__(256) void k_transpose(const float* __restrict__ inp,
                                                   float* __restrict__ x) {
    __shared__ float tile[64][41];
    int b  = blockIdx.y;
    int d0 = blockIdx.x * 64;
    const float* ip = inp + (size_t)b * (D_ * S_);
    for (int idx = threadIdx.x; idx < 64 * 40; idx += 256) {
        int i = idx / 40, s = idx - i * 40;
        if (d0 + i < D_) tile[i][s] = ip[(size_t)(d0 + i) * S_ + s];
    }
    __syncthreads();
    float* xp = x + (size_t)b * (D_ * S_);
    for (int idx = threadIdx.x; idx < 40 * 64; idx += 256) {
        int j = idx & 63, s = idx >> 6;
        if (d0 + j < D_) xp[(size_t)s * D_ + d0 + j] = tile[j][s];
    }
}

// ---------------------------------------------------------------------------
// 1) MERGED LN: x += h (optional, writeback) + row stats + LN apply + f16.
//    One wave per row; the 564-f32 row lives in 9 registers across both
//    phases -> saves the 23 MB x re-read and one dispatch per layer.
//    h layout (S, B, KP) f16.  hA MUST NOT alias h (read/write same kernel).
// ---------------------------------------------------------------------------
__global__ __launch_bounds__(256) void k_ln(float* __restrict__ x,
                                            const f16* __restrict__ h,
                                            int addh,
                                            const float* __restrict__ lg,
                                            const float* __restrict__ lb,
                                            f16* __restrict__ hA) {
    int row  = blockIdx.x * 4 + (threadIdx.x >> 6);
    int lane = threadIdx.x & 63;
    float* xp = x + (size_t)row * D_;
    int b = row / S_, s = row - b * S_;
    const f16* hp = h + ((size_t)s * B_ + b) * KP_;
    float v[9];
    float s1 = 0.f, s2 = 0.f;
#pragma unroll
    for (int j = 0; j < 9; ++j) {
        int i = lane + j * 64;
        float t = 0.f;
        if (i < D_) {
            t = xp[i];
            if (addh) { t += (float)hp[i]; xp[i] = t; }
        }
        v[j] = t;
        s1 += t;
        s2 += t * t;
    }
    for (int off = 32; off; off >>= 1) {
        s1 += __shfl_down(s1, off);
        s2 += __shfl_down(s2, off);
    }
    s1 = __shfl(s1, 0);
    s2 = __shfl(s2, 0);
    float mu  = s1 * (1.f / D_);
    float var = fmaxf(s2 * (1.f / D_) - mu * mu, 0.f);
    float rs  = rsqrtf(var + 1e-5f);
    f16* op = hA + (size_t)row * KP_;
#pragma unroll
    for (int j = 0; j < 9; ++j) {
        int i = lane + j * 64;
        float o = (i < D_) ? (v[j] - mu) * rs * lg[i] + lb[i] : 0.f;
        op[i] = (f16)o;      // i < 576 always (9*64 = 576)
    }
}

// ---------------------------------------------------------------------------
// 2) pre-GEMM (MFMA fp16), 256x128 tile, 8 waves (4M x 2N), BK=32, linear
//    LDS, global_load_lds 16B staging (3 DMAs/thread/iter vs 4 at 128x128:
//    B-panel reuse doubled, per-output barriers halved).  Bijective XCD
//    swizzle (720 = 8 x 90).  Gate-interleaved Wt -> coalesced epilogue.
// ---------------------------------------------------------------------------
__global__ __launch_bounds__(512) void k_pregemm(const f16* __restrict__ hA,
                                                 const f16* __restrict__ Wt,  // (2256, 576) c=e*4+g
                                                 const float* __restrict__ bgl,
                                                 f16* __restrict__ pre2) {
    __shared__ __align__(16) f16 As[256 * 32];
    __shared__ __align__(16) f16 Bs[128 * 32];
    const int tid  = threadIdx.x;
    const int wave = tid >> 6, lane = tid & 63;
    const int quad = lane >> 4, l16 = lane & 15;
    const int wm = wave >> 1, wn = wave & 1;

    int wg  = blockIdx.x;                    // 720 = 8 XCDs x 90
    int swz = (wg & 7) * 90 + (wg >> 3);
    int by  = swz / 40, bx = swz - by * 40;
    const int m0 = bx * 256, n0 = by * 128;

    const int srow = tid >> 2, scol = (tid & 3) * 8;
    const f16* gaA0 = hA + (size_t)(m0 + srow) * KP_ + scol;
    const f16* gaA1 = gaA0 + (size_t)128 * KP_;
    int bc = n0 + srow; if (bc >= N_) bc = N_ - 1;   // clamp: cols skipped in epilogue
    const f16* gbB = Wt + (size_t)bc * KP_ + scol;
    f16* lA0 = As + wave * 512;          // wave-uniform LDS bases
    f16* lA1 = As + 4096 + wave * 512;
    f16* lB  = Bs + wave * 512;

    f32x4 acc[4][4];
#pragma unroll
    for (int i = 0; i < 4; ++i)
#pragma unroll
        for (int j = 0; j < 4; ++j) acc[i][j] = (f32x4){0.f, 0.f, 0.f, 0.f};

    for (int k0 = 0; k0 < KP_; k0 += 32) {
        gload16(gaA0 + k0, lA0);
        gload16(gaA1 + k0, lA1);
        gload16(gbB + k0, lB);
        __syncthreads();               // compiler drains vmcnt(0) before barrier
        f16x8 bf[4];
#pragma unroll
        for (int fn = 0; fn < 4; ++fn)
            bf[fn] = *(const f16x8*)(Bs + (wn * 64 + fn * 16 + l16) * 32 + quad * 8);
#pragma unroll
        for (int fm = 0; fm < 4; ++fm) {
            f16x8 af = *(const f16x8*)(As + (wm * 64 + fm * 16 + l16) * 32 + quad * 8);
#pragma unroll
            for (int fn = 0; fn < 4; ++fn)
                acc[fm][fn] = __builtin_amdgcn_mfma_f32_16x16x32_f16(
                                  af, bf[fn], acc[fm][fn], 0, 0, 0);
        }
        __syncthreads();               // protect LDS before next-step DMA
    }

#pragma unroll
    for (int fn = 0; fn < 4; ++fn) {
        int ncol = n0 + wn * 64 + fn * 16 + l16;
        if (ncol >= N_) continue;
        float bias = bgl[(ncol & 3) * D_ + (ncol >> 2)];   // bg is (gate, D)
#pragma unroll
        for (int fm = 0; fm < 4; ++fm) {
            int mbase = m0 + wm * 64 + fm * 16 + quad * 4;
#pragma unroll
            for (int r = 0; r < 4; ++r) {
                int mm = mbase + r;
                int bb = mm / S_, ss2 = mm - bb * S_;
                pre2[(size_t)(ss2 * B_ + bb) * N_ + ncol] =
                    (f16)(acc[fm][fn][r] + bias);
            }
        }
    }
}

// ---------------------------------------------------------------------------
// 3) persistent sLSTM recurrence — round-1 protocol VERBATIM (measured best,
//    130.7 us/dispatch): shared per-bg padded counters, tid==0 sc0sc1 poll,
//    agent-scope h loads/stores, vmcnt-draining syncthreads + RMW arrive
//    (RMW REQUIRED: plain-store arrive raced).  gbuf stride-17, rcpf gates.
// ---------------------------------------------------------------------------
__global__ __launch_bounds__(576, 1) void k_rec_persist(
        const f16* __restrict__ Rt,      // (4,564,576) layer slice
        const f16* __restrict__ pre2,    // (40,256,564,4) f16
        unsigned* __restrict__ hbuf,     // (40, 256, 288) u32
        unsigned* __restrict__ bar,      // 16 counters, stride BSTRIDE_ u32
        int layer) {
    __shared__ __align__(16) f16 hs[16 * 584];         // h tile, padded rows
    __shared__ __align__(16) float gbuf[144 * 17 + 2]; // stride-17: conflict-free

    const int tid  = threadIdx.x;
    const int et   = blockIdx.x;
    const int bg   = blockIdx.y;
    const int wave = tid >> 6, lane = tid & 63;
    const int quad = lane >> 4, l16 = lane & 15;

    const int c  = wave * 16 + l16;
    const int g  = c / 36, el = c - g * 36;
    const int e  = et * 36 + el;
    const int ec = (e < D_) ? e : D_ - 1;

    f16x8 breg[18];
    {
        const f16* rp = Rt + (size_t)(g * D_ + ec) * KP_ + quad * 8;
#pragma unroll
        for (int kc = 0; kc < 18; ++kc)
            breg[kc] = *(const f16x8*)(rp + kc * 32);
    }

    const int b_loc = tid & 15, el2 = tid >> 4;
    const int e2  = et * 36 + el2;
    const int b   = bg * 16 + b_loc;
    const bool eok = (e2 < D_);
    const int ec2 = eok ? e2 : D_ - 1;

    float cv = 0.f, nv = 0.f, mv = 0.f;

    unsigned* barp = bar + bg * BSTRIDE_;
    const unsigned base = (unsigned)layer * 640u;

    f16x4 pf = *(const f16x4*)(pre2 + (size_t)b * D_ * 4 + ec2 * 4);

    for (int t = 0; t < S_; ++t) {
        if (t > 0) {
            if (tid == 0) {
                unsigned tgt = base + 16u * (unsigned)t;
                for (;;) {
                    unsigned v;
                    asm volatile(
                        "global_load_dword %0, %1, off sc0 sc1\n\t"
                        "s_waitcnt vmcnt(0)"
                        : "=v"(v) : "v"(barp) : "memory");
                    if (v >= tgt) break;
                    __builtin_amdgcn_s_sleep(1);
                }
            }
            __syncthreads();
            const unsigned long long* hsrc = (const unsigned long long*)
                (hbuf + (size_t)(t - 1) * (B_ * HW_) + (size_t)bg * 16 * HW_);
#pragma unroll
            for (int p = 0; p < 4; ++p) {
                int ch  = tid + p * 576;
                int row = ch / 144, col = ch - row * 144;
                unsigned long long v = __hip_atomic_load(
                    hsrc + (size_t)row * 144 + col,
                    __ATOMIC_RELAXED, __HIP_MEMORY_SCOPE_AGENT);
                *(unsigned long long*)(hs + row * 584 + col * 4) = v;
            }
            __syncthreads();
            f32x4 a0 = (f32x4){0.f, 0.f, 0.f, 0.f};
            f32x4 a1 = (f32x4){0.f, 0.f, 0.f, 0.f};
            const f16* hl = hs + l16 * 584 + quad * 8;
#pragma unroll
            for (int kc = 0; kc < 18; kc += 2) {
                f16x8 f0 = *(const f16x8*)(hl + kc * 32);
                f16x8 f1 = *(const f16x8*)(hl + kc * 32 + 32);
                a0 = __builtin_amdgcn_mfma_f32_16x16x32_f16(f0, breg[kc],     a0, 0, 0, 0);
                a1 = __builtin_amdgcn_mfma_f32_16x16x32_f16(f1, breg[kc + 1], a1, 0, 0, 0);
            }
            f32x4 acc = a0 + a1;
#pragma unroll
            for (int r = 0; r < 4; ++r)
                gbuf[c * 17 + quad * 4 + r] = acc[r];
            __syncthreads();
        }

        float hn = 0.f;
        if (eok) {
            float it = (float)pf[0];
            float ft = (float)pf[1];
            float zt = (float)pf[2];
            float ot = (float)pf[3];
            if (t > 0) {
                it += gbuf[(0 * 36 + el2) * 17 + b_loc];
                ft += gbuf[(1 * 36 + el2) * 17 + b_loc];
                zt += gbuf[(2 * 36 + el2) * 17 + b_loc];
                ot += gbuf[(3 * 36 + el2) * 17 + b_loc];
            }
            float mn = fmaxf(ft + mv, it);
            float iv = __expf(it - mn);
            float fv = __expf(ft + mv - mn);
            // tanh(z) = 1 - 2/(exp(2z)+1): exact at +/-inf, NaN-free
            float th = 1.f - 2.f * __builtin_amdgcn_rcpf(__expf(2.f * zt) + 1.f);
            float cn = fv * cv + iv * th;
            float nn = fv * nv + iv;
            float sg = __builtin_amdgcn_rcpf(1.f + __expf(-ot));
            hn = cn * __builtin_amdgcn_rcpf(fmaxf(nn, 1e-6f)) * sg;
            cv = cn; nv = nn; mv = mn;
        }

        unsigned short h16 = __builtin_bit_cast(unsigned short, (f16)hn);
        int other = __shfl_xor((int)h16, 16);
        if ((el2 & 1) == 0) {
            unsigned word = (unsigned)h16 | ((unsigned)(unsigned short)other << 16);
            __hip_atomic_store(hbuf + (size_t)t * (B_ * HW_)
                                    + (size_t)b * HW_ + et * 18 + (el2 >> 1),
                               word, __ATOMIC_RELAXED, __HIP_MEMORY_SCOPE_AGENT);
        }

        // arrive: syncthreads drains vmcnt in every wave; RMW arrive lands
        // behind the drained h stores at the coherence point.
        __syncthreads();
        if (tid == 0)
            __hip_atomic_fetch_add(barp, 1u, __ATOMIC_RELAXED,
                                   __HIP_MEMORY_SCOPE_AGENT);

        if (t + 1 < S_)
            pf = *(const f16x4*)(pre2 + ((size_t)(t + 1) * B_ + b) * D_ * 4
                                      + ec2 * 4);
    }
}

// ---------------------------------------------------------------------------
// 4) BatchNorm part 1: fold in layer-5 h (x += h, writeback) + partial sums.
// ---------------------------------------------------------------------------
__global__ __launch_bounds__(256) void k_bnpart(float* __restrict__ x,
                                                const f16* __restrict__ h,
                                                float* __restrict__ part) {
    int b = blockIdx.x;
    for (int c = threadIdx.x; c < D_; c += 256) {
        float s1 = 0.f, s2 = 0.f;
        for (int t = 0; t < S_; ++t) {
            size_t xi = (size_t)(b * S_ + t) * D_ + c;
            float v = x[xi] + (float)h[((size_t)t * B_ + b) * KP_ + c];
            x[xi] = v;
            s1 += v;
            s2 += v * v;
        }
        part[(size_t)b * 1152 + c]       = s1;
        part[(size_t)b * 1152 + 576 + c] = s2;
    }
}

__global__ __launch_bounds__(64) void k_bnfinal(const float* __restrict__ part,
                                                const float* __restrict__ bn_g,
                                                const float* __restrict__ bn_b,
                                                float* __restrict__ sc,
                                                float* __restrict__ sh) {
    int d = blockIdx.x * 64 + threadIdx.x;
    if (d >= D_) return;
    float s1 = 0.f, s2 = 0.f;
    for (int w = 0; w < 256; ++w) {
        s1 += part[(size_t)w * 1152 + d];
        s2 += part[(size_t)w * 1152 + 576 + d];
    }
    float mu  = s1 * (1.f / M_);
    float var = fmaxf(s2 * (1.f / M_) - mu * mu, 0.f);
    float s   = bn_g[d] * rsqrtf(var + 1e-5f);
    sc[d] = s;
    sh[d] = bn_b[d] - mu * s;
}

// ---------------------------------------------------------------------------
// 5) final projection + tanh
// ---------------------------------------------------------------------------
__global__ __launch_bounds__(128) void k_final(const float* __restrict__ x,
                                               const float* __restrict__ sc,
                                               const float* __restrict__ sh,
                                               const float* __restrict__ w6,
                                               const float* __restrict__ b6,
                                               float* __restrict__ out) {
    int b = blockIdx.x / 20;
    int p = blockIdx.x - b * 20;
    float a0 = 0.f, a1 = 0.f;
    for (int q = threadIdx.x; q < OUTIN_; q += 128) {
        int u = p * OUTIN_ + q;
        int d = u / 40, s = u - d * 40;
        float v = x[((size_t)b * S_ + s) * D_ + d] * sc[d] + sh[d];
        a0 = fmaf(v, w6[q * 2 + 0], a0);
        a1 = fmaf(v, w6[q * 2 + 1], a1);
    }
    __shared__ float r0[128], r1[128];
    r0[threadIdx.x] = a0;
    r1[threadIdx.x] = a1;
    __syncthreads();
    for (int off = 64; off; off >>= 1) {
        if (threadIdx.x < off) {
            r0[threadIdx.x] += r0[threadIdx.x + off];
            r1[threadIdx.x] += r1[threadIdx.x + off];
        }
        __syncthreads();
    }
    if (threadIdx.x == 0) {
        out[((size_t)b * 20 + p) * 2 + 0] = tanhf(r0[0] + b6[0]);
        out[((size_t)b * 20 + p) * 2 + 1] = tanhf(r1[0] + b6[1]);
    }
}

// ---------------------------------------------------------------------------
extern "C" void kernel_launch(void* const* d_in, const int* in_sizes, int n_in,
                              void* d_out, int out_size, void* d_ws, size_t ws_size,
                              hipStream_t stream) {
    const float* inp  = (const float*)d_in[0];
    const float* Wg   = (const float*)d_in[1];
    const float* Rg   = (const float*)d_in[2];
    const float* bg   = (const float*)d_in[3];
    const float* ln_g = (const float*)d_in[4];
    const float* ln_b = (const float*)d_in[5];
    const float* bn_g = (const float*)d_in[6];
    const float* bn_b = (const float*)d_in[7];
    const float* w6   = (const float*)d_in[8];
    const float* b6   = (const float*)d_in[9];
    float* out = (float*)d_out;

    float* ws = (float*)d_ws;
    size_t off = 0;
    float*    x    = ws + off;            off += (size_t)M_ * D_;           // 23.1 MB
    f16*      pre2 = (f16*)(ws + off);    off += (size_t)M_ * N_ / 2;       // 46.2 MB
    f16*      hA   = (f16*)(ws + off);    off += (size_t)M_ * KP_ / 2;      // 11.8 MB
    unsigned* hbuf = (unsigned*)(ws + off); off += (size_t)M_ * KP_ / 2;    // 11.8 MB (separate: k_ln reads hbuf while writing hA)
    f16*      Wt   = (f16*)(ws + off);    off += (size_t)NB_ * 4 * D_ * KP_ / 2;
    f16*      Rt   = (f16*)(ws + off);    off += (size_t)NB_ * 4 * D_ * KP_ / 2;
    float*    part = ws + off;            off += 256 * 1152;
    float*    sc   = ws + off;            off += 576;
    float*    sh   = ws + off;            off += 576;
    unsigned* bar  = (unsigned*)(ws + off); off += 16 * BSTRIDE_;

    hipMemsetAsync(bar, 0, 16 * BSTRIDE_ * sizeof(unsigned), stream);

    k_prep<<<dim3(18, 18, 48), 256, 0, stream>>>(Wg, Rg, Wt, Rt);
    k_transpose<<<dim3(9, B_), 256, 0, stream>>>(inp, x);

    for (int l = 0; l < NB_; ++l) {
        const f16*   Wtl = Wt + (size_t)l * 4 * D_ * KP_;
        const f16*   Rtl = Rt + (size_t)l * 4 * D_ * KP_;
        const float* bgl = bg + (size_t)l * N_;
        const float* lgl = ln_g + (size_t)l * D_;
        const float* lbl = ln_b + (size_t)l * D_;

        k_ln<<<M_ / 4, 256, 0, stream>>>(x, (const f16*)hbuf, l > 0 ? 1 : 0,
                                         lgl, lbl, hA);
        k_pregemm<<<720, 512, 0, stream>>>(hA, Wtl, bgl, pre2);
        k_rec_persist<<<dim3(16, 16), 576, 0, stream>>>(Rtl, pre2, hbuf, bar, l);
    }

    k_bnpart<<<B_, 256, 0, stream>>>(x, (const f16*)hbuf, part);
    k_bnfinal<<<9, 64, 0, stream>>>(part, bn_g, bn_b, sc, sh);
    k_final<<<B_ * 20, 128, 0, stream>>>(x, sc, sh, w6, b6, out);
}